// Round 7
// baseline (527.973 us; speedup 1.0000x reference)
//
#include <hip/hip_runtime.h>
#include <math.h>

#define D_MODEL 768
#define D_HID   1536
#define N_BATCH 8
#define SEQLEN  2048
#define NROWS   (N_BATCH*SEQLEN)   // 16384

typedef unsigned short u16;
typedef unsigned char  u8;
typedef __attribute__((ext_vector_type(8))) short bfrag;   // 8 x bf16 (4 VGPRs)
typedef __attribute__((ext_vector_type(4))) float facc;    // 4 x fp32 acc

__device__ __forceinline__ u16 f2bf(float f) {
  unsigned u = __float_as_uint(f);
  u += 0x7fffu + ((u >> 16) & 1u);
  return (u16)(u >> 16);
}
__device__ __forceinline__ float bf2f(u16 u) {
  return __uint_as_float((unsigned)u << 16);
}
__device__ __forceinline__ u8 f2fp8(float f) {   // OCP e4m3 on gfx950
  return (u8)(__builtin_amdgcn_cvt_pk_fp8_f32(f, f, 0, 0) & 0xff);
}

__device__ __forceinline__ void async16(const void* g, void* l) {
  __builtin_amdgcn_global_load_lds((const __attribute__((address_space(1))) void*)g,
                                   (__attribute__((address_space(3))) void*)l,
                                   16, 0, 0);
}
// raw barrier: no implicit vmcnt(0) drain (unlike __syncthreads), full compiler fence
__device__ __forceinline__ void wg_barrier() {
  asm volatile("" ::: "memory");
  __builtin_amdgcn_s_barrier();
  asm volatile("" ::: "memory");
}
#define VMCNT(n) asm volatile("s_waitcnt vmcnt(" #n ")" ::: "memory")
#define LGK0     asm volatile("s_waitcnt lgkmcnt(0)" ::: "memory")

// ------- fused f32->bf16 conversion of all operands + bias concat + LSUM zero -------
__global__ __launch_bounds__(256) void cvt_all(
    const float* __restrict__ x,  const float* __restrict__ Wq,
    const float* __restrict__ Wk, const float* __restrict__ Wv,
    const float* __restrict__ Wp, const float* __restrict__ W1,
    const float* __restrict__ W2, const float* __restrict__ bq,
    const float* __restrict__ bk, const float* __restrict__ bv,
    u16* __restrict__ XB, u16* __restrict__ WQKV, u16* __restrict__ WPB,
    u16* __restrict__ W1B, u16* __restrict__ W2B, float* __restrict__ BQKV,
    float* __restrict__ LSUM) {
  long i = (long)blockIdx.x * 256 + threadIdx.x;
  const float* src; u16* dst; long off;
  if      (i < 3145728) { src = x;  dst = XB;             off = i; }
  else if (i < 3293184) { src = Wq; dst = WQKV;           off = i - 3145728; }
  else if (i < 3440640) { src = Wk; dst = WQKV + 589824;  off = i - 3293184; }
  else if (i < 3588096) { src = Wv; dst = WQKV + 1179648; off = i - 3440640; }
  else if (i < 3735552) { src = Wp; dst = WPB;            off = i - 3588096; }
  else if (i < 4030464) { src = W1; dst = W1B;            off = i - 3735552; }
  else if (i < 4325376) { src = W2; dst = W2B;            off = i - 4030464; }
  else if (i < 4325952) {
    long j = i - 4325376;   // 0..575 -> BQKV[j] (f4), concatenated bq|bk|bv
    const float* s = (j < 192) ? bq : (j < 384) ? bk : bv;
    long o = (j < 192) ? j : (j < 384) ? j - 192 : j - 384;
    ((float4*)BQKV)[j] = ((const float4*)s)[o];
    return;
  } else if (i < 4330048) {
    float4 zz = {0.f, 0.f, 0.f, 0.f};
    ((float4*)LSUM)[i - 4325952] = zz;
    return;
  } else return;
  float4 v = ((const float4*)src)[off];
  ushort4 o4;
  o4.x = f2bf(v.x); o4.y = f2bf(v.y); o4.z = f2bf(v.z); o4.w = f2bf(v.w);
  *reinterpret_cast<ushort4*>(dst + off * 4) = o4;
}

enum { EPI_EXP = 1, EPI_DIV = 2, EPI_GELU = 4, EPI_QKV = 5, EPI_RES = 6 };

// ===== GEMM bf16 QKV: C = A*B^T, tile 128x256, BK=32, 8 waves, 3-buffer + reg-dbuf =====
// Fragment register double-buffer: at iter t, regs hold tile t (read last iter); issue
// tile t+1's 8 ds_reads into the other set + stage tile t+3, then MFMA tile t with NO
// lgkm dependency -> LDS drains under the MFMA phase. Lead-3 staging, vmcnt(3) = tile
// t+1 landed. lgkmcnt(0) at iter top drains own reads of buf(t%3) before the barrier,
// so STAGE(t+3)->buf(t%3) is race-free across waves.
__global__ __launch_bounds__(512, 2)
void gemm_bt512(const u16* __restrict__ Aall, const u16* __restrict__ Ball,
                void* __restrict__ Cout,
                int M, int N, int K,
                long sA, long sB, long sC,
                const float* __restrict__ bias,
                const u16* __restrict__ residVT,  // VT out (fp8)
                float* __restrict__ lsum, float scale)
{
  __shared__ __align__(16) char smem[73728];
  const u16* A = Aall;
  const u16* B = Ball;
  const int bm = blockIdx.x, bn = blockIdx.y;
  const int tid = (int)threadIdx.x;
  const int lane = tid & 63, wv = tid >> 6;
  const int wr = wv >> 2, wc = wv & 3;               // wave grid 2x4 (64x64 each)

  facc acc[4][4] = {};

  const int srow2 = tid >> 2;                         // 0..127
  const int c4 = tid & 3;
  const int skey = (srow2 >> 1) & 3;
  const int sc = ((c4 ^ skey) << 3);                  // source elem offset in row
  const u16* Abase = A + (long)(bm * 128) * K;
  const u16* Bbase = B + (long)(bn * 256) * K;
  const int fr = lane & 15, g0 = lane >> 4;
  const int rkey = (fr >> 1) & 3;
  const int nt = K >> 5;                              // 24 (even)

  auto STAGE = [&](int t, int b) {
    char* Asb = smem + b * 24576;
    char* Bsb = Asb + 8192;
    const long k0 = (long)t << 5;
    async16(Abase + (long)srow2 * K + k0 + sc, Asb + tid * 16);
#pragma unroll
    for (int p = 0; p < 2; ++p)
      async16(Bbase + (long)(p * 128 + srow2) * K + k0 + sc, Bsb + p * 8192 + tid * 16);
  };

#define RD512(AF, BF, b) do {                                                   \
    const u16* As_ = (const u16*)(smem + (b) * 24576);                          \
    const u16* Bs_ = As_ + 4096;                                                \
    _Pragma("unroll") for (int i = 0; i < 4; ++i) {                             \
      const int r = wr * 64 + i * 16 + fr;                                      \
      AF[i] = *(const bfrag*)(As_ + r * 32 + ((g0 ^ rkey) << 3));               \
    }                                                                           \
    _Pragma("unroll") for (int j = 0; j < 4; ++j) {                             \
      const int r = wc * 64 + j * 16 + fr;                                      \
      BF[j] = *(const bfrag*)(Bs_ + r * 32 + ((g0 ^ rkey) << 3));               \
    }                                                                           \
  } while (0)

#define FMA512(AF, BF) do {                                                     \
    __builtin_amdgcn_s_setprio(1);                                              \
    _Pragma("unroll") for (int i = 0; i < 4; ++i)                               \
    _Pragma("unroll") for (int j = 0; j < 4; ++j)                               \
      acc[i][j] = __builtin_amdgcn_mfma_f32_16x16x32_bf16(AF[i], BF[j],         \
                                                          acc[i][j], 0, 0, 0); \
    __builtin_amdgcn_s_setprio(0);                                              \
  } while (0)

  bfrag afA[4], bfA[4], afB[4], bfB[4];
  STAGE(0, 0); STAGE(1, 1); STAGE(2, 2);
  VMCNT(6);            // tile 0 landed (tiles 1,2 in flight)
  wg_barrier();
  RD512(afA, bfA, 0);  // tile 0 -> set A

  int bs = 0;          // (t+3)%3 cycles 0,1,2 from t=0
  int rn = 1;          // (t+1)%3 cycles 1,2,0 from t=0
  for (int t = 0; t < nt; t += 2) {
    // even half: cur = A, next = B
    if (t < nt - 2) { VMCNT(3); } else { VMCNT(0); }
    LGK0;                             // own reads of buf(t%3) complete
    wg_barrier();
    if (t + 3 < nt) STAGE(t + 3, bs);
    if (t + 1 < nt) RD512(afB, bfB, rn);
    FMA512(afA, bfA);
    bs = (bs == 2) ? 0 : bs + 1;
    rn = (rn == 2) ? 0 : rn + 1;
    // odd half: cur = B, next = A   (nt even)
    const int u = t + 1;
    if (u < nt - 2) { VMCNT(3); } else { VMCNT(0); }
    LGK0;
    wg_barrier();
    if (u + 3 < nt) STAGE(u + 3, bs);
    if (u + 1 < nt) RD512(afA, bfA, rn);
    FMA512(afB, bfB);
    bs = (bs == 2) ? 0 : bs + 1;
    rn = (rn == 2) ? 0 : rn + 1;
  }
  wg_barrier();   // all reads done before epilogue overlays LDS
#undef RD512
#undef FMA512

  // ---- QKV epilogue (8-wave): fp8 out; Q,K row-major; V transposed ----
  const int rb = bm * 128 + wr * 64;
  const int cb = bn * 256 + wc * 64;
  const int quad = lane >> 4;
  const int c64 = bn * 4 + wc;         // 0..35
  const int which = c64 / 12;          // 0=Q,1=K,2=V
  float bj[4];
#pragma unroll
  for (int j = 0; j < 4; ++j) bj[j] = bias[cb + j * 16 + fr];
  if (which == 2) {
    u8* VT_ = (u8*)residVT;
    const int zb = rb >> 11;
    const int seqb = (rb & 2047) + quad * 4;
    const int dimb = (c64 - 24) * 64;
#pragma unroll
    for (int i = 0; i < 4; ++i) {
#pragma unroll
      for (int j = 0; j < 4; ++j) {
        const int dim = dimb + j * 16 + fr;
        unsigned v01 = __builtin_amdgcn_cvt_pk_fp8_f32(acc[i][j][0] + bj[j],
                                                       acc[i][j][1] + bj[j], 0, 0);
        unsigned v23 = __builtin_amdgcn_cvt_pk_fp8_f32(acc[i][j][2] + bj[j],
                                                       acc[i][j][3] + bj[j], 0, 0);
        unsigned w = (v01 & 0xffffu) | (v23 << 16);
        *reinterpret_cast<unsigned*>(VT_ + (long)zb * D_MODEL * SEQLEN +
                                     (long)dim * SEQLEN + seqb + i * 16) = w;
      }
    }
    return;
  }
  u8* ep8 = (u8*)(smem + wv * 8192);   // 64x64 fp8 per wave
  u8* Cg = (u8*)Cout + (long)which * NROWS * D_MODEL;
  const int cbo = (c64 - which * 12) * 64;
#pragma unroll
  for (int i = 0; i < 4; ++i)
#pragma unroll
    for (int r = 0; r < 4; ++r) {
      const int lrow = i * 16 + quad * 4 + r;
#pragma unroll
      for (int j = 0; j < 4; ++j)
        ep8[lrow * 64 + j * 16 + fr] = f2fp8(acc[i][j][r] + bj[j]);
    }
#pragma unroll
  for (int it = 0; it < 4; ++it) {
    const int lr = it * 16 + (lane >> 2);
    const int ch = (lane & 3) << 4;
    int4 d = *(const int4*)(ep8 + lr * 64 + ch);
    *reinterpret_cast<int4*>(Cg + (long)(rb + lr) * D_MODEL + cbo + ch) = d;
  }
  (void)lsum; (void)scale; (void)M; (void)sA; (void)sB; (void)sC;
}

// ===== GEMM bf16: C = A*B^T, tile 128x128, BK=32, 4 waves, triple-buffered (round-5) =====
template<int EPI>
__global__ __launch_bounds__(256, 3)
void gemm_bt(const u16* __restrict__ Aall, const u16* __restrict__ Ball,
             void* __restrict__ Cout,
             int M, int N, int K,
             long sA, long sB, long sC,
             const float* __restrict__ bias,
             const u16* __restrict__ resid,
             float* __restrict__ lsum,
             float scale)
{
  __shared__ __align__(16) char smem[49152];
  const int z = blockIdx.z;
  const u16* A = Aall + (long)z * sA;
  const u16* B = Ball + (long)z * sB;
  const int bm = blockIdx.x, bn = blockIdx.y;
  const int tid = (int)threadIdx.x;
  const int lane = tid & 63, wv = tid >> 6;
  const int wr = wv >> 1, wc = wv & 1;               // wave grid 2x2 (64x64 each)

  facc acc[4][4] = {};

  const int srow2 = tid >> 2;                         // 0..63
  const int c4 = tid & 3;
  const int skey = (srow2 >> 1) & 3;
  const int sc = ((c4 ^ skey) << 3);
  const u16* Abase = A + (long)(bm * 128) * K;
  const u16* Bbase = B + (long)(bn * 128) * K;
  const int fr = lane & 15, g0 = lane >> 4;
  const int rkey = (fr >> 1) & 3;
  const int nt = K >> 5;

  auto STAGE = [&](int t, int b) {
    char* Asb = smem + b * 16384;
    char* Bsb = Asb + 8192;
    const long k0 = (long)t << 5;
#pragma unroll
    for (int p = 0; p < 2; ++p) {
      async16(Abase + (long)(p * 64 + srow2) * K + k0 + sc, Asb + p * 4096 + tid * 16);
      async16(Bbase + (long)(p * 64 + srow2) * K + k0 + sc, Bsb + p * 4096 + tid * 16);
    }
  };

  STAGE(0, 0); STAGE(1, 1);
  int rb_ = 0, sb_ = 2;
  for (int t = 0; t < nt; ++t) {
    if (t < nt - 1) { VMCNT(4); } else { VMCNT(0); }
    wg_barrier();
    if (t + 2 < nt) STAGE(t + 2, sb_);
    const u16* As = (const u16*)(smem + rb_ * 16384);
    const u16* Bs = As + 4096;
    bfrag af[4], bf[4];
#pragma unroll
    for (int i = 0; i < 4; ++i) {
      const int r = wr * 64 + i * 16 + fr;
      af[i] = *(const bfrag*)(As + r * 32 + ((g0 ^ rkey) << 3));
    }
#pragma unroll
    for (int j = 0; j < 4; ++j) {
      const int r = wc * 64 + j * 16 + fr;
      bf[j] = *(const bfrag*)(Bs + r * 32 + ((g0 ^ rkey) << 3));
    }
    __builtin_amdgcn_s_setprio(1);
#pragma unroll
    for (int i = 0; i < 4; ++i)
#pragma unroll
      for (int j = 0; j < 4; ++j)
        acc[i][j] = __builtin_amdgcn_mfma_f32_16x16x32_bf16(af[i], bf[j], acc[i][j], 0, 0, 0);
    __builtin_amdgcn_s_setprio(0);
    rb_ = (rb_ == 2) ? 0 : rb_ + 1;
    sb_ = (sb_ == 2) ? 0 : sb_ + 1;
  }
  wg_barrier();

  const int rb = bm * 128 + wr * 64;
  const int cb = bn * 128 + wc * 64;
  const int quad = lane >> 4;

  if constexpr (EPI == EPI_GELU) {
    u16* ep16 = (u16*)(smem + wv * 8192);
    u16* Cg = (u16*)Cout + (long)z * sC;
    float bj[4];
#pragma unroll
    for (int j = 0; j < 4; ++j) bj[j] = bias[cb + j * 16 + fr];
#pragma unroll
    for (int i = 0; i < 4; ++i) {
#pragma unroll
      for (int r = 0; r < 4; ++r) {
        const int lrow = i * 16 + quad * 4 + r;
#pragma unroll
        for (int j = 0; j < 4; ++j) {
          float t = acc[i][j][r] + bj[j];
          float y = 0.7978845608f * (t + 0.044715f * t * t * t);
          float e = __expf(-2.f * fabsf(y));
          float th = (1.f - e) / (1.f + e);
          th = (y < 0.f) ? -th : th;
          ep16[lrow * 64 + j * 16 + fr] = f2bf(0.5f * t * (1.f + th));
        }
      }
    }
#pragma unroll
    for (int it = 0; it < 8; ++it) {
      const int lr = it * 8 + (lane >> 3);
      const int ch = (lane & 7) << 3;
      int4 d = *(const int4*)(ep16 + lr * 64 + ch);
      *reinterpret_cast<int4*>(Cg + (long)(rb + lr) * N + cb + ch) = d;
    }
  } else {
    // EPI_RES: bf16 out = acc + bias + bf16 residual (two 32-row f32 half-passes)
    float* ep32 = (float*)(smem + wv * 8192);
    u16* Cg = (u16*)Cout;
#pragma unroll
    for (int h = 0; h < 2; ++h) {
#pragma unroll
      for (int i2 = 0; i2 < 2; ++i2) {
        const int i = h * 2 + i2;
#pragma unroll
        for (int r = 0; r < 4; ++r) {
          const int lrow = i2 * 16 + quad * 4 + r;
#pragma unroll
          for (int j = 0; j < 4; ++j)
            ep32[lrow * 64 + j * 16 + fr] = acc[i][j][r];
        }
      }
#pragma unroll
      for (int it = 0; it < 8; ++it) {
        const int lr = it * 4 + (lane >> 4);
        const int ch = (lane & 15) << 2;
        float4 d = *(const float4*)(ep32 + lr * 64 + ch);
        const int row = rb + h * 32 + lr;
        const int gcol = cb + ch;
        const long gi = (long)row * N + gcol;
        ushort4 rv = *(const ushort4*)(resid + gi);
        float4 bb = *(const float4*)(bias + gcol);
        ushort4 o;
        o.x = f2bf(d.x + bb.x + bf2f(rv.x));
        o.y = f2bf(d.y + bb.y + bf2f(rv.y));
        o.z = f2bf(d.z + bb.z + bf2f(rv.z));
        o.w = f2bf(d.w + bb.w + bf2f(rv.w));
        *reinterpret_cast<ushort4*>(Cg + gi) = o;
      }
      wg_barrier();
    }
  }
  (void)lsum; (void)scale; (void)M; (void)resid; (void)bias;
}

// ===== GEMM fp8 e4m3: C = A*B^T, tile 128x128, BK=64B, 4 waves, 3-buffer + reg-dbuf =====
// Same reg-dbuf pipeline as gemm_bt512 (lead-3, vmcnt(4)=tile t+1 landed, lgkmcnt(0)
// drain before barrier). Frags: 16 x b64 per tile per wave (32 VGPR both sets).
template<int EPI>
__global__ __launch_bounds__(256, 3)
void gemm_f8(const u8* __restrict__ Aall, const u8* __restrict__ Ball,
             void* __restrict__ Cout,
             int M, int N, int K,           // K in elements == bytes
             long sA, long sB, long sC,
             float* __restrict__ lsum, float scale)
{
  __shared__ __align__(16) char smem[49152];
  const int z = blockIdx.z;
  const u8* A = Aall + (long)z * sA;
  const u8* B = Ball + (long)z * sB;
  const int bm = blockIdx.x, bn = blockIdx.y;
  const int tid = (int)threadIdx.x;
  const int lane = tid & 63, wv = tid >> 6;
  const int wr = wv >> 1, wc = wv & 1;

  facc acc[4][4] = {};

  const int srow2 = tid >> 2;                          // 0..63
  const int c4 = tid & 3;
  const int skey = (srow2 >> 1) & 3;
  const int scb = ((c4 ^ skey) << 4);
  const u8* Abase = A + (long)(bm * 128) * K;
  const u8* Bbase = B + (long)(bn * 128) * K;
  const int fr = lane & 15, g0 = lane >> 4;
  const int rkey = (fr >> 1) & 3;
  const int nt = K >> 6;                               // 12 or 32 (even)

  auto STAGE = [&](int t, int b) {
    char* Asb = smem + b * 16384;
    char* Bsb = Asb + 8192;
    const long k0 = (long)t << 6;
#pragma unroll
    for (int p = 0; p < 2; ++p) {
      async16(Abase + (long)(p * 64 + srow2) * K + k0 + scb, Asb + p * 4096 + tid * 16);
      async16(Bbase + (long)(p * 64 + srow2) * K + k0 + scb, Bsb + p * 4096 + tid * 16);
    }
  };

#define RDF8(AF, BF, b) do {                                                    \
    const u8* As_ = (const u8*)(smem + (b) * 16384);                            \
    const u8* Bs_ = As_ + 8192;                                                 \
    _Pragma("unroll") for (int s = 0; s < 2; ++s) {                             \
      const int cc = (s * 2 + (g0 >> 1)) ^ rkey;                                \
      const int h8 = (g0 & 1) << 3;                                             \
      _Pragma("unroll") for (int i = 0; i < 4; ++i) {                           \
        const int r = wr * 64 + i * 16 + fr;                                    \
        AF[s][i] = *(const long*)(As_ + r * 64 + (cc << 4) + h8);               \
      }                                                                         \
      _Pragma("unroll") for (int j = 0; j < 4; ++j) {                           \
        const int r = wc * 64 + j * 16 + fr;                                    \
        BF[s][j] = *(const long*)(Bs_ + r * 64 + (cc << 4) + h8);               \
      }                                                                         \
    }                                                                           \
  } while (0)

#define FMAF8(AF, BF) do {                                                      \
    __builtin_amdgcn_s_setprio(1);                                              \
    _Pragma("unroll") for (int s = 0; s < 2; ++s)                               \
    _Pragma("unroll") for (int i = 0; i < 4; ++i)                               \
    _Pragma("unroll") for (int j = 0; j < 4; ++j)                               \
      acc[i][j] = __builtin_amdgcn_mfma_f32_16x16x32_fp8_fp8(AF[s][i], BF[s][j],\
                                                             acc[i][j], 0, 0, 0);\
    __builtin_amdgcn_s_setprio(0);                                              \
  } while (0)

  long afA[2][4], bfA[2][4], afB[2][4], bfB[2][4];
  STAGE(0, 0); STAGE(1, 1); STAGE(2, 2);
  VMCNT(8);            // tile 0 landed (tiles 1,2 in flight)
  wg_barrier();
  RDF8(afA, bfA, 0);

  int bs = 0, rn = 1;
  for (int t = 0; t < nt; t += 2) {
    if (t < nt - 2) { VMCNT(4); } else { VMCNT(0); }
    LGK0;
    wg_barrier();
    if (t + 3 < nt) STAGE(t + 3, bs);
    if (t + 1 < nt) RDF8(afB, bfB, rn);
    FMAF8(afA, bfA);
    bs = (bs == 2) ? 0 : bs + 1;
    rn = (rn == 2) ? 0 : rn + 1;
    const int u = t + 1;
    if (u < nt - 2) { VMCNT(4); } else { VMCNT(0); }
    LGK0;
    wg_barrier();
    if (u + 3 < nt) STAGE(u + 3, bs);
    if (u + 1 < nt) RDF8(afA, bfA, rn);
    FMAF8(afB, bfB);
    bs = (bs == 2) ? 0 : bs + 1;
    rn = (rn == 2) ? 0 : rn + 1;
  }
  wg_barrier();
#undef RDF8
#undef FMAF8

  const int rb = bm * 128 + wr * 64;
  const int cb = bn * 128 + wc * 64;
  const int quad = lane >> 4;

  if constexpr (EPI == EPI_EXP) {
    // E' = exp(alpha - 3) in fp8 (range ~[e^-5, e^-1]); rowsums to lsum.
    u8* ep8 = (u8*)(smem + wv * 4096);
    u8* Cg = (u8*)Cout + (long)z * sC;
#pragma unroll
    for (int i = 0; i < 4; ++i) {
#pragma unroll
      for (int r = 0; r < 4; ++r) {
        const int lrow = i * 16 + quad * 4 + r;
        const int row = rb + lrow;
        float rs = 0.f;
#pragma unroll
        for (int j = 0; j < 4; ++j) {
          float e = __expf(acc[i][j][r] * scale - 3.0f);
          rs += e;
          ep8[lrow * 64 + j * 16 + fr] = f2fp8(e);
        }
        rs += __shfl_xor(rs, 1);
        rs += __shfl_xor(rs, 2);
        rs += __shfl_xor(rs, 4);
        rs += __shfl_xor(rs, 8);
        if (fr == 0) atomicAdd(&lsum[(long)z * M + row], rs);
      }
    }
#pragma unroll
    for (int it = 0; it < 4; ++it) {
      const int lr = it * 16 + (lane >> 2);
      const int ch = (lane & 3) << 4;
      int4 d = *(const int4*)(ep8 + lr * 64 + ch);
      *reinterpret_cast<int4*>(Cg + (long)(rb + lr) * N + cb + ch) = d;
    }
  } else {
    // EPI_DIV: bf16 out = acc / lsum, staged in two 32-row half-passes (4 KB/wave)
    u16* ep16 = (u16*)(smem + wv * 4096);
    u16* Cg = (u16*)Cout + (long)z * sC;
#pragma unroll
    for (int h = 0; h < 2; ++h) {
#pragma unroll
      for (int i2 = 0; i2 < 2; ++i2) {
        const int i = h * 2 + i2;
#pragma unroll
        for (int r = 0; r < 4; ++r) {
          const int lrow = i2 * 16 + quad * 4 + r;
          const int row = rb + h * 32 + lrow;
          const float inv = 1.f / lsum[(long)z * M + row];
#pragma unroll
          for (int j = 0; j < 4; ++j)
            ep16[lrow * 64 + j * 16 + fr] = f2bf(acc[i][j][r] * inv);
        }
      }
#pragma unroll
      for (int it = 0; it < 4; ++it) {
        const int lr = it * 8 + (lane >> 3);
        const int ch = (lane & 7) << 3;
        int4 d = *(const int4*)(ep16 + lr * 64 + ch);
        *reinterpret_cast<int4*>(Cg + (long)(rb + h * 32 + lr) * N + cb + ch) = d;
      }
      wg_barrier();
    }
  }
}

// ---------------- LayerNorm over rows of 768, bf16 in ----------------
__global__ __launch_bounds__(192) void layernorm_rows(const u16* __restrict__ in,
                                                      const float* __restrict__ gamma,
                                                      const float* __restrict__ beta,
                                                      float* __restrict__ outf,
                                                      u16* __restrict__ outb) {
  const int row = blockIdx.x;
  const int t = threadIdx.x;
  ushort4 uv = ((const ushort4*)(in + (long)row * D_MODEL))[t];
  float v0 = bf2f(uv.x), v1 = bf2f(uv.y), v2 = bf2f(uv.z), v3 = bf2f(uv.w);
  float s1 = v0 + v1 + v2 + v3;
  float s2 = v0 * v0 + v1 * v1 + v2 * v2 + v3 * v3;
#pragma unroll
  for (int o = 32; o; o >>= 1) { s1 += __shfl_xor(s1, o); s2 += __shfl_xor(s2, o); }
  __shared__ float r1[3], r2[3];
  const int wv = t >> 6, ln = t & 63;
  if (ln == 0) { r1[wv] = s1; r2[wv] = s2; }
  __syncthreads();
  s1 = r1[0] + r1[1] + r1[2];
  s2 = r2[0] + r2[1] + r2[2];
  const float mu = s1 * (1.f / 768.f);
  const float var = s2 * (1.f / 768.f) - mu * mu;
  const float rstd = rsqrtf(var + 1e-12f);
  float4 gv = ((const float4*)gamma)[t];
  float4 bv = ((const float4*)beta)[t];
  float o0 = (v0 - mu) * rstd * gv.x + bv.x;
  float o1 = (v1 - mu) * rstd * gv.y + bv.y;
  float o2 = (v2 - mu) * rstd * gv.z + bv.z;
  float o3 = (v3 - mu) * rstd * gv.w + bv.w;
  if (outf) {
    float4 ov = {o0, o1, o2, o3};
    ((float4*)(outf + (long)row * D_MODEL))[t] = ov;
  }
  if (outb) {
    ushort4 ob;
    ob.x = f2bf(o0); ob.y = f2bf(o1); ob.z = f2bf(o2); ob.w = f2bf(o3);
    ((ushort4*)(outb + (long)row * D_MODEL))[t] = ob;
  }
}

// ---------------- workspace layout (bytes), stream-ordered aliasing ----------------
static const size_t OFF_WP   = 0;          // 1179648
static const size_t OFF_W1   = 1179648;    // 2359296
static const size_t OFF_W2   = 3538944;    // 2359296 -> 5898240
static const size_t OFF_LSUM = 5898240;    // 65536
static const size_t OFF_BQKV = 5963776;    // 9216 (pad to 6291456)
static const size_t OFF_QB   = 6291456;    // fp8 12582912  (QB,KB contiguous)
static const size_t OFF_KB   = 18874368;   // fp8 12582912
static const size_t OFF_VT   = 31457280;   // fp8 12582912 [dead after DIV]
static const size_t OFF_EB   = 44040192;   // fp8 33554432 [dead after DIV]
static const size_t OFF_CTX  = 77594624;   // bf16 25165824 [dead after proj]
static const size_t OFF_XB   = 102760448;  // bf16 25165824 [dead after proj]
static const size_t OFF_WQKV = 127926272;  // bf16 3538944 -> 131465216
static const size_t OFF_M1B  = 131465216;  // bf16 50331648 -> 181796864 total
// aliases: PB=QB+KB (25 MB); HB=EB head (25 MB); M2B=CTX region

extern "C" void kernel_launch(void* const* d_in, const int* in_sizes, int n_in,
                              void* d_out, int out_size, void* d_ws, size_t ws_size,
                              hipStream_t stream) {
  const float* x   = (const float*)d_in[0];
  const float* Wq  = (const float*)d_in[1];
  const float* bq  = (const float*)d_in[2];
  const float* Wk  = (const float*)d_in[3];
  const float* bk  = (const float*)d_in[4];
  const float* Wv  = (const float*)d_in[5];
  const float* bv  = (const float*)d_in[6];
  const float* Wp  = (const float*)d_in[7];
  const float* bp  = (const float*)d_in[8];
  const float* g1  = (const float*)d_in[9];
  const float* be1 = (const float*)d_in[10];
  const float* W1  = (const float*)d_in[11];
  const float* b1  = (const float*)d_in[12];
  const float* W2  = (const float*)d_in[13];
  const float* b2  = (const float*)d_in[14];
  const float* g2  = (const float*)d_in[15];
  const float* be2 = (const float*)d_in[16];

  char* ws = (char*)d_ws;
  u16*   WPB  = (u16*)(ws + OFF_WP);
  u16*   W1B  = (u16*)(ws + OFF_W1);
  u16*   W2B  = (u16*)(ws + OFF_W2);
  float* LSUM = (float*)(ws + OFF_LSUM);
  float* BQKV = (float*)(ws + OFF_BQKV);
  u8*    QB   = (u8*)(ws + OFF_QB);
  u8*    KB   = (u8*)(ws + OFF_KB);
  u8*    VT   = (u8*)(ws + OFF_VT);
  u8*    EB   = (u8*)(ws + OFF_EB);
  u16*   CTX  = (u16*)(ws + OFF_CTX);
  u16*   XB   = (u16*)(ws + OFF_XB);
  u16*   WQKV = (u16*)(ws + OFF_WQKV);
  u16*   M1B  = (u16*)(ws + OFF_M1B);
  // aliases (stream-ordered lifetimes)
  u16*   PB   = (u16*)(ws + OFF_QB);    // after EXP frees QB+KB
  u16*   HB   = (u16*)(ws + OFF_EB);    // after DIV frees EB
  u16*   M2B  = (u16*)(ws + OFF_CTX);   // after proj frees CTX

  dim3 blk(256), blkg(512), blkl(192);

  // all f32->bf16 conversions + bias concat + LSUM zero, one kernel
  cvt_all<<<dim3(16915), blk, 0, stream>>>(x, Wq, Wk, Wv, Wp, W1, W2, bq, bk, bv,
                                           XB, WQKV, WPB, W1B, W2B, BQKV, LSUM);

  // fused QKV projection (bf16 core, fp8 outputs): Q,K row-major fp8; V -> VT fp8 transposed
  gemm_bt512<<<dim3(128, 9, 1), blkg, 0, stream>>>(XB, WQKV, QB,
      NROWS, 3 * D_MODEL, D_MODEL, 0, 0, 0, BQKV, (const u16*)VT, nullptr, 0.f);

  // scores: E' = exp(Q K^T / sqrt(D) - 3) fp8, row sums into LSUM (offset cancels in DIV)
  const float sc = 1.0f / sqrtf((float)D_MODEL);
  gemm_f8<EPI_EXP><<<dim3(16, 16, 8), blk, 0, stream>>>(QB, KB, EB,
      SEQLEN, SEQLEN, D_MODEL,
      (long)SEQLEN * D_MODEL, (long)SEQLEN * D_MODEL, (long)SEQLEN * SEQLEN,
      LSUM, sc);
  // context: Ctx = (E' V) / lsum'  (bf16 out); grid 16x6x8 = 768 = 1.0 round at 3/CU
  gemm_f8<EPI_DIV><<<dim3(16, 6, 8), blk, 0, stream>>>(EB, VT, CTX,
      SEQLEN, D_MODEL, SEQLEN,
      (long)SEQLEN * SEQLEN, (long)D_MODEL * SEQLEN, (long)SEQLEN * D_MODEL,
      LSUM, 0.f);
  // proj + residual (bf16): PB = bf16(x + Ctx Wp^T + bp); 768 blocks = 1.0 round
  gemm_bt<EPI_RES><<<dim3(128, 6, 1), blk, 0, stream>>>(CTX, WPB, PB,
      NROWS, D_MODEL, D_MODEL, 0, 0, 0, bp, XB, nullptr, 0.f);
  // LN1 -> HB (bf16)
  layernorm_rows<<<dim3(NROWS), blkl, 0, stream>>>(PB, g1, be1, nullptr, HB);
  // MLP1 + tanh-gelu -> M1B (bf16); 1536 blocks = 2.0 rounds
  gemm_bt<EPI_GELU><<<dim3(128, 12, 1), blk, 0, stream>>>(HB, W1B, M1B,
      NROWS, D_HID, D_MODEL, 0, 0, 0, b1, nullptr, nullptr, 0.f);
  // MLP2 + residual (bf16): M2B = bf16(h + M1 W2^T + b2); 768 blocks = 1.0 round
  gemm_bt<EPI_RES><<<dim3(128, 6, 1), blk, 0, stream>>>(M1B, W2B, M2B,
      NROWS, D_MODEL, D_HID, 0, 0, 0, b2, HB, nullptr, 0.f);
  // LN2 -> d_out (fp32)
  layernorm_rows<<<dim3(NROWS), blkl, 0, stream>>>(M2B, g2, be2, (float*)d_out, nullptr);

  (void)in_sizes; (void)n_in; (void)out_size; (void)ws_size;
}

// Round 8
// 463.825 us; speedup vs baseline: 1.1383x; 1.1383x over previous
//
#include <hip/hip_runtime.h>
#include <math.h>

#define D_MODEL 768
#define D_HID   1536
#define N_BATCH 8
#define SEQLEN  2048
#define NROWS   (N_BATCH*SEQLEN)   // 16384

typedef unsigned short u16;
typedef unsigned char  u8;
typedef __attribute__((ext_vector_type(8))) short bfrag;   // 8 x bf16 (4 VGPRs)
typedef __attribute__((ext_vector_type(4))) float facc;    // 4 x fp32 acc

__device__ __forceinline__ u16 f2bf(float f) {
  unsigned u = __float_as_uint(f);
  u += 0x7fffu + ((u >> 16) & 1u);
  return (u16)(u >> 16);
}
__device__ __forceinline__ float bf2f(u16 u) {
  return __uint_as_float((unsigned)u << 16);
}
__device__ __forceinline__ u8 f2fp8(float f) {   // OCP e4m3 on gfx950
  return (u8)(__builtin_amdgcn_cvt_pk_fp8_f32(f, f, 0, 0) & 0xff);
}

__device__ __forceinline__ void async16(const void* g, void* l) {
  __builtin_amdgcn_global_load_lds((const __attribute__((address_space(1))) void*)g,
                                   (__attribute__((address_space(3))) void*)l,
                                   16, 0, 0);
}
// raw barrier: no implicit vmcnt(0) drain (unlike __syncthreads), full compiler fence
__device__ __forceinline__ void wg_barrier() {
  asm volatile("" ::: "memory");
  __builtin_amdgcn_s_barrier();
  asm volatile("" ::: "memory");
}
#define VMCNT(n) asm volatile("s_waitcnt vmcnt(" #n ")" ::: "memory")

// ------- fused f32->bf16 conversion of all operands + bias concat + LSUM zero -------
__global__ __launch_bounds__(256) void cvt_all(
    const float* __restrict__ x,  const float* __restrict__ Wq,
    const float* __restrict__ Wk, const float* __restrict__ Wv,
    const float* __restrict__ Wp, const float* __restrict__ W1,
    const float* __restrict__ W2, const float* __restrict__ bq,
    const float* __restrict__ bk, const float* __restrict__ bv,
    u16* __restrict__ XB, u16* __restrict__ WQKV, u16* __restrict__ WPB,
    u16* __restrict__ W1B, u16* __restrict__ W2B, float* __restrict__ BQKV,
    float* __restrict__ LSUM) {
  long i = (long)blockIdx.x * 256 + threadIdx.x;
  const float* src; u16* dst; long off;
  if      (i < 3145728) { src = x;  dst = XB;             off = i; }
  else if (i < 3293184) { src = Wq; dst = WQKV;           off = i - 3145728; }
  else if (i < 3440640) { src = Wk; dst = WQKV + 589824;  off = i - 3293184; }
  else if (i < 3588096) { src = Wv; dst = WQKV + 1179648; off = i - 3440640; }
  else if (i < 3735552) { src = Wp; dst = WPB;            off = i - 3588096; }
  else if (i < 4030464) { src = W1; dst = W1B;            off = i - 3735552; }
  else if (i < 4325376) { src = W2; dst = W2B;            off = i - 4030464; }
  else if (i < 4325952) {
    long j = i - 4325376;   // 0..575 -> BQKV[j] (f4), concatenated bq|bk|bv
    const float* s = (j < 192) ? bq : (j < 384) ? bk : bv;
    long o = (j < 192) ? j : (j < 384) ? j - 192 : j - 384;
    ((float4*)BQKV)[j] = ((const float4*)s)[o];
    return;
  } else if (i < 4330048) {
    float4 zz = {0.f, 0.f, 0.f, 0.f};
    ((float4*)LSUM)[i - 4325952] = zz;
    return;
  } else return;
  float4 v = ((const float4*)src)[off];
  ushort4 o4;
  o4.x = f2bf(v.x); o4.y = f2bf(v.y); o4.z = f2bf(v.z); o4.w = f2bf(v.w);
  *reinterpret_cast<ushort4*>(dst + off * 4) = o4;
}

enum { EPI_EXP = 1, EPI_DIV = 2, EPI_GELU = 4, EPI_QKV = 5, EPI_RES = 6 };

// ===== GEMM bf16 QKV: C = A*B^T, tile 128x256, BK=32, 8 waves (512 thr), triple-buffered =====
// Round-5 structure (best measured): counted vmcnt, no drain, (r>>1)&3 swizzle.
__global__ __launch_bounds__(512, 2)
void gemm_bt512(const u16* __restrict__ Aall, const u16* __restrict__ Ball,
                void* __restrict__ Cout,
                int M, int N, int K,
                long sA, long sB, long sC,
                const float* __restrict__ bias,
                const u16* __restrict__ residVT,  // VT out (fp8)
                float* __restrict__ lsum, float scale)
{
  __shared__ __align__(16) char smem[73728];
  const u16* A = Aall;
  const u16* B = Ball;
  const int bm = blockIdx.x, bn = blockIdx.y;
  const int tid = (int)threadIdx.x;
  const int lane = tid & 63, wv = tid >> 6;
  const int wr = wv >> 2, wc = wv & 3;               // wave grid 2x4 (64x64 each)

  facc acc[4][4] = {};

  const int srow2 = tid >> 2;                         // 0..127
  const int c4 = tid & 3;
  const int skey = (srow2 >> 1) & 3;
  const int sc = ((c4 ^ skey) << 3);                  // source elem offset in row
  const u16* Abase = A + (long)(bm * 128) * K;
  const u16* Bbase = B + (long)(bn * 256) * K;
  const int fr = lane & 15, g0 = lane >> 4;
  const int rkey = (fr >> 1) & 3;
  const int nt = K >> 5;                              // 24

  auto STAGE = [&](int t, int b) {
    char* Asb = smem + b * 24576;
    char* Bsb = Asb + 8192;
    const long k0 = (long)t << 5;
    async16(Abase + (long)srow2 * K + k0 + sc, Asb + tid * 16);
#pragma unroll
    for (int p = 0; p < 2; ++p)
      async16(Bbase + (long)(p * 128 + srow2) * K + k0 + sc, Bsb + p * 8192 + tid * 16);
  };

  STAGE(0, 0); STAGE(1, 1);
  int rb_ = 0, sb_ = 2;
  for (int t = 0; t < nt; ++t) {
    if (t < nt - 1) { VMCNT(3); } else { VMCNT(0); }  // tile t landed; t+1 stays in flight
    wg_barrier();                                     // all waves: t in LDS, t-1 reads done
    if (t + 2 < nt) STAGE(t + 2, sb_);
    const u16* As = (const u16*)(smem + rb_ * 24576);
    const u16* Bs = As + 4096;
    bfrag af[4], bf[4];
#pragma unroll
    for (int i = 0; i < 4; ++i) {
      const int r = wr * 64 + i * 16 + fr;
      af[i] = *(const bfrag*)(As + r * 32 + ((g0 ^ rkey) << 3));
    }
#pragma unroll
    for (int j = 0; j < 4; ++j) {
      const int r = wc * 64 + j * 16 + fr;
      bf[j] = *(const bfrag*)(Bs + r * 32 + ((g0 ^ rkey) << 3));
    }
    __builtin_amdgcn_s_setprio(1);
#pragma unroll
    for (int i = 0; i < 4; ++i)
#pragma unroll
      for (int j = 0; j < 4; ++j)
        acc[i][j] = __builtin_amdgcn_mfma_f32_16x16x32_bf16(af[i], bf[j], acc[i][j], 0, 0, 0);
    __builtin_amdgcn_s_setprio(0);
    rb_ = (rb_ == 2) ? 0 : rb_ + 1;
    sb_ = (sb_ == 2) ? 0 : sb_ + 1;
  }
  wg_barrier();   // all reads done before epilogue overlays LDS

  // ---- QKV epilogue (8-wave): fp8 out; Q,K row-major; V transposed ----
  const int rb = bm * 128 + wr * 64;
  const int cb = bn * 256 + wc * 64;
  const int quad = lane >> 4;
  const int c64 = bn * 4 + wc;         // 0..35
  const int which = c64 / 12;          // 0=Q,1=K,2=V (boundaries at multiples of 4)
  float bj[4];
#pragma unroll
  for (int j = 0; j < 4; ++j) bj[j] = bias[cb + j * 16 + fr];
  if (which == 2) {
    u8* VT_ = (u8*)residVT;
    const int zb = rb >> 11;
    const int seqb = (rb & 2047) + quad * 4;
    const int dimb = (c64 - 24) * 64;
#pragma unroll
    for (int i = 0; i < 4; ++i) {
#pragma unroll
      for (int j = 0; j < 4; ++j) {
        const int dim = dimb + j * 16 + fr;
        unsigned v01 = __builtin_amdgcn_cvt_pk_fp8_f32(acc[i][j][0] + bj[j],
                                                       acc[i][j][1] + bj[j], 0, 0);
        unsigned v23 = __builtin_amdgcn_cvt_pk_fp8_f32(acc[i][j][2] + bj[j],
                                                       acc[i][j][3] + bj[j], 0, 0);
        unsigned w = (v01 & 0xffffu) | (v23 << 16);
        *reinterpret_cast<unsigned*>(VT_ + (long)zb * D_MODEL * SEQLEN +
                                     (long)dim * SEQLEN + seqb + i * 16) = w;
      }
    }
    return;
  }
  u8* ep8 = (u8*)(smem + wv * 8192);   // 64x64 fp8 per wave
  u8* Cg = (u8*)Cout + (long)which * NROWS * D_MODEL;
  const int cbo = (c64 - which * 12) * 64;
#pragma unroll
  for (int i = 0; i < 4; ++i)
#pragma unroll
    for (int r = 0; r < 4; ++r) {
      const int lrow = i * 16 + quad * 4 + r;
#pragma unroll
      for (int j = 0; j < 4; ++j)
        ep8[lrow * 64 + j * 16 + fr] = f2fp8(acc[i][j][r] + bj[j]);
    }
#pragma unroll
  for (int it = 0; it < 4; ++it) {
    const int lr = it * 16 + (lane >> 2);
    const int ch = (lane & 3) << 4;
    int4 d = *(const int4*)(ep8 + lr * 64 + ch);
    *reinterpret_cast<int4*>(Cg + (long)(rb + lr) * D_MODEL + cbo + ch) = d;
  }
  (void)lsum; (void)scale; (void)M; (void)sA; (void)sB; (void)sC;
}

// ===== GEMM bf16: C = A*B^T, tile 128x128, BK=32, 4 waves (256 thr), triple-buffered =====
template<int EPI>
__global__ __launch_bounds__(256, 3)
void gemm_bt(const u16* __restrict__ Aall, const u16* __restrict__ Ball,
             void* __restrict__ Cout,
             int M, int N, int K,
             long sA, long sB, long sC,
             const float* __restrict__ bias,
             const u16* __restrict__ resid,
             float* __restrict__ lsum,
             float scale)
{
  __shared__ __align__(16) char smem[49152];
  const int z = blockIdx.z;
  const u16* A = Aall + (long)z * sA;
  const u16* B = Ball + (long)z * sB;
  const int bm = blockIdx.x, bn = blockIdx.y;
  const int tid = (int)threadIdx.x;
  const int lane = tid & 63, wv = tid >> 6;
  const int wr = wv >> 1, wc = wv & 1;               // wave grid 2x2 (64x64 each)

  facc acc[4][4] = {};

  const int srow2 = tid >> 2;                         // 0..63
  const int c4 = tid & 3;
  const int skey = (srow2 >> 1) & 3;
  const int sc = ((c4 ^ skey) << 3);
  const u16* Abase = A + (long)(bm * 128) * K;
  const u16* Bbase = B + (long)(bn * 128) * K;
  const int fr = lane & 15, g0 = lane >> 4;
  const int rkey = (fr >> 1) & 3;
  const int nt = K >> 5;

  auto STAGE = [&](int t, int b) {
    char* Asb = smem + b * 16384;
    char* Bsb = Asb + 8192;
    const long k0 = (long)t << 5;
#pragma unroll
    for (int p = 0; p < 2; ++p) {
      async16(Abase + (long)(p * 64 + srow2) * K + k0 + sc, Asb + p * 4096 + tid * 16);
      async16(Bbase + (long)(p * 64 + srow2) * K + k0 + sc, Bsb + p * 4096 + tid * 16);
    }
  };

  STAGE(0, 0); STAGE(1, 1);
  int rb_ = 0, sb_ = 2;
  for (int t = 0; t < nt; ++t) {
    if (t < nt - 1) { VMCNT(4); } else { VMCNT(0); }
    wg_barrier();
    if (t + 2 < nt) STAGE(t + 2, sb_);
    const u16* As = (const u16*)(smem + rb_ * 16384);
    const u16* Bs = As + 4096;
    bfrag af[4], bf[4];
#pragma unroll
    for (int i = 0; i < 4; ++i) {
      const int r = wr * 64 + i * 16 + fr;
      af[i] = *(const bfrag*)(As + r * 32 + ((g0 ^ rkey) << 3));
    }
#pragma unroll
    for (int j = 0; j < 4; ++j) {
      const int r = wc * 64 + j * 16 + fr;
      bf[j] = *(const bfrag*)(Bs + r * 32 + ((g0 ^ rkey) << 3));
    }
    __builtin_amdgcn_s_setprio(1);
#pragma unroll
    for (int i = 0; i < 4; ++i)
#pragma unroll
      for (int j = 0; j < 4; ++j)
        acc[i][j] = __builtin_amdgcn_mfma_f32_16x16x32_bf16(af[i], bf[j], acc[i][j], 0, 0, 0);
    __builtin_amdgcn_s_setprio(0);
    rb_ = (rb_ == 2) ? 0 : rb_ + 1;
    sb_ = (sb_ == 2) ? 0 : sb_ + 1;
  }
  wg_barrier();

  const int rb = bm * 128 + wr * 64;
  const int cb = bn * 128 + wc * 64;
  const int quad = lane >> 4;

  if constexpr (EPI == EPI_GELU) {
    u16* ep16 = (u16*)(smem + wv * 8192);
    u16* Cg = (u16*)Cout + (long)z * sC;
    float bj[4];
#pragma unroll
    for (int j = 0; j < 4; ++j) bj[j] = bias[cb + j * 16 + fr];
#pragma unroll
    for (int i = 0; i < 4; ++i) {
#pragma unroll
      for (int r = 0; r < 4; ++r) {
        const int lrow = i * 16 + quad * 4 + r;
#pragma unroll
        for (int j = 0; j < 4; ++j) {
          float t = acc[i][j][r] + bj[j];
          float y = 0.7978845608f * (t + 0.044715f * t * t * t);
          float e = __expf(-2.f * fabsf(y));
          float th = (1.f - e) / (1.f + e);
          th = (y < 0.f) ? -th : th;
          ep16[lrow * 64 + j * 16 + fr] = f2bf(0.5f * t * (1.f + th));
        }
      }
    }
#pragma unroll
    for (int it = 0; it < 8; ++it) {
      const int lr = it * 8 + (lane >> 3);
      const int ch = (lane & 7) << 3;
      int4 d = *(const int4*)(ep16 + lr * 64 + ch);
      *reinterpret_cast<int4*>(Cg + (long)(rb + lr) * N + cb + ch) = d;
    }
  } else {
    // EPI_RES: bf16 out = acc + bias + bf16 residual (two 32-row f32 half-passes)
    float* ep32 = (float*)(smem + wv * 8192);
    u16* Cg = (u16*)Cout;
#pragma unroll
    for (int h = 0; h < 2; ++h) {
#pragma unroll
      for (int i2 = 0; i2 < 2; ++i2) {
        const int i = h * 2 + i2;
#pragma unroll
        for (int r = 0; r < 4; ++r) {
          const int lrow = i2 * 16 + quad * 4 + r;
#pragma unroll
          for (int j = 0; j < 4; ++j)
            ep32[lrow * 64 + j * 16 + fr] = acc[i][j][r];
        }
      }
#pragma unroll
      for (int it = 0; it < 8; ++it) {
        const int lr = it * 4 + (lane >> 4);
        const int ch = (lane & 15) << 2;
        float4 d = *(const float4*)(ep32 + lr * 64 + ch);
        const int row = rb + h * 32 + lr;
        const int gcol = cb + ch;
        const long gi = (long)row * N + gcol;
        ushort4 rv = *(const ushort4*)(resid + gi);
        float4 bb = *(const float4*)(bias + gcol);
        ushort4 o;
        o.x = f2bf(d.x + bb.x + bf2f(rv.x));
        o.y = f2bf(d.y + bb.y + bf2f(rv.y));
        o.z = f2bf(d.z + bb.z + bf2f(rv.z));
        o.w = f2bf(d.w + bb.w + bf2f(rv.w));
        *reinterpret_cast<ushort4*>(Cg + gi) = o;
      }
      wg_barrier();
    }
  }
  (void)lsum; (void)scale; (void)M; (void)resid; (void)bias;
}

// ===== GEMM fp8 e4m3: C = A*B^T, tile 128x128, BK=64 bytes, 4 waves =====
// DEPTH=3: triple-buffer 48KB, 3 blocks/CU. DEPTH=2: double-buffer 32KB, 4 blocks/CU (EXP).
// lsum is now a PARTITIONED partial-sum array: EXP plain-stores its 64-col partial to
// slot (z*M+row)*32 + bn*2 + wc (single writer, no atomics, no init); DIV gathers the
// 32 partials via float2-per-lane + the existing shfl_xor tree. Removes 524K cross-XCD
// atomic RMWs (~40MB write amplification seen in round-7 counters).
template<int EPI, int DEPTH>
__global__ __launch_bounds__(256, 6 - DEPTH)
void gemm_f8(const u8* __restrict__ Aall, const u8* __restrict__ Ball,
             void* __restrict__ Cout,
             int M, int N, int K,           // K in elements == bytes
             long sA, long sB, long sC,
             float* __restrict__ lsum, float scale)
{
  __shared__ __align__(16) char smem[DEPTH * 16384];
  const int z = blockIdx.z;
  const u8* A = Aall + (long)z * sA;
  const u8* B = Ball + (long)z * sB;
  const int bm = blockIdx.x, bn = blockIdx.y;
  const int tid = (int)threadIdx.x;
  const int lane = tid & 63, wv = tid >> 6;
  const int wr = wv >> 1, wc = wv & 1;

  facc acc[4][4] = {};

  const int srow2 = tid >> 2;                          // 0..63
  const int c4 = tid & 3;
  const int skey = (srow2 >> 1) & 3;
  const int scb = ((c4 ^ skey) << 4);
  const u8* Abase = A + (long)(bm * 128) * K;
  const u8* Bbase = B + (long)(bn * 128) * K;
  const int fr = lane & 15, g0 = lane >> 4;
  const int rkey = (fr >> 1) & 3;
  const int nt = K >> 6;

  auto STAGE = [&](int t, int b) {
    char* Asb = smem + b * 16384;
    char* Bsb = Asb + 8192;
    const long k0 = (long)t << 6;
#pragma unroll
    for (int p = 0; p < 2; ++p) {
      async16(Abase + (long)(p * 64 + srow2) * K + k0 + scb, Asb + p * 4096 + tid * 16);
      async16(Bbase + (long)(p * 64 + srow2) * K + k0 + scb, Bsb + p * 4096 + tid * 16);
    }
  };

  auto COMPUTE = [&](int buf) {
    const u8* As = (const u8*)(smem + buf * 16384);
    const u8* Bs = As + 8192;
#pragma unroll
    for (int s = 0; s < 2; ++s) {     // 2 K-substeps of 32 fp8
      long af[4], bf[4];
      const int cc = (s * 2 + (g0 >> 1)) ^ rkey;
      const int h8 = (g0 & 1) << 3;
#pragma unroll
      for (int i = 0; i < 4; ++i) {
        const int r = wr * 64 + i * 16 + fr;
        af[i] = *(const long*)(As + r * 64 + (cc << 4) + h8);
      }
#pragma unroll
      for (int j = 0; j < 4; ++j) {
        const int r = wc * 64 + j * 16 + fr;
        bf[j] = *(const long*)(Bs + r * 64 + (cc << 4) + h8);
      }
      __builtin_amdgcn_s_setprio(1);
#pragma unroll
      for (int i = 0; i < 4; ++i)
#pragma unroll
        for (int j = 0; j < 4; ++j)
          acc[i][j] = __builtin_amdgcn_mfma_f32_16x16x32_fp8_fp8(af[i], bf[j], acc[i][j], 0, 0, 0);
      __builtin_amdgcn_s_setprio(0);
    }
  };

  if constexpr (DEPTH == 3) {
    STAGE(0, 0); STAGE(1, 1);
    int rb_ = 0, sb_ = 2;
    for (int t = 0; t < nt; ++t) {
      if (t < nt - 1) { VMCNT(4); } else { VMCNT(0); }
      wg_barrier();
      if (t + 2 < nt) STAGE(t + 2, sb_);
      COMPUTE(rb_);
      rb_ = (rb_ == 2) ? 0 : rb_ + 1;
      sb_ = (sb_ == 2) ? 0 : sb_ + 1;
    }
    wg_barrier();
  } else {
    STAGE(0, 0); STAGE(1, 1);
    for (int t = 0; t < nt; ++t) {
      if (t < nt - 1) { VMCNT(4); } else { VMCNT(0); }
      wg_barrier();                 // tile t in LDS for all waves
      COMPUTE(t & 1);
      wg_barrier();                 // all waves done reading buf t&1
      if (t + 2 < nt) STAGE(t + 2, t & 1);
    }
  }

  const int rb = bm * 128 + wr * 64;
  const int cb = bn * 128 + wc * 64;
  const int quad = lane >> 4;

  if constexpr (EPI == EPI_EXP) {
    // E' = exp(alpha - 3) in fp8 (range ~[e^-5, e^-1]); 64-col partial row-sums ->
    // private slot (z*M+row)*32 + bn*2 + wc, plain store (no atomics).
    u8* ep8 = (u8*)(smem + wv * 4096);
    u8* Cg = (u8*)Cout + (long)z * sC;
#pragma unroll
    for (int i = 0; i < 4; ++i) {
#pragma unroll
      for (int r = 0; r < 4; ++r) {
        const int lrow = i * 16 + quad * 4 + r;
        const int row = rb + lrow;
        float rs = 0.f;
#pragma unroll
        for (int j = 0; j < 4; ++j) {
          float e = __expf(acc[i][j][r] * scale - 3.0f);
          rs += e;
          ep8[lrow * 64 + j * 16 + fr] = f2fp8(e);
        }
        rs += __shfl_xor(rs, 1);
        rs += __shfl_xor(rs, 2);
        rs += __shfl_xor(rs, 4);
        rs += __shfl_xor(rs, 8);
        if (fr == 0)
          lsum[(((long)z * M + row) << 5) + (bn << 1) + wc] = rs;
      }
    }
#pragma unroll
    for (int it = 0; it < 4; ++it) {
      const int lr = it * 16 + (lane >> 2);
      const int ch = (lane & 3) << 4;
      int4 d = *(const int4*)(ep8 + lr * 64 + ch);
      *reinterpret_cast<int4*>(Cg + (long)(rb + lr) * N + cb + ch) = d;
    }
  } else {
    // EPI_DIV: bf16 out = acc / rowsum; rowsum = Sum of 32 partials, gathered as
    // float2-per-lane (fr*2) + shfl_xor tree within each 16-lane group.
    u16* ep16 = (u16*)(smem + wv * 4096);
    u16* Cg = (u16*)Cout + (long)z * sC;
#pragma unroll
    for (int h = 0; h < 2; ++h) {
#pragma unroll
      for (int i2 = 0; i2 < 2; ++i2) {
        const int i = h * 2 + i2;
#pragma unroll
        for (int r = 0; r < 4; ++r) {
          const int lrow = i2 * 16 + quad * 4 + r;
          const int row = rb + h * 32 + lrow;
          const float2 p2 = *reinterpret_cast<const float2*>(
              lsum + (((long)z * M + row) << 5) + (fr << 1));
          float ls = p2.x + p2.y;
          ls += __shfl_xor(ls, 1);
          ls += __shfl_xor(ls, 2);
          ls += __shfl_xor(ls, 4);
          ls += __shfl_xor(ls, 8);
          const float inv = 1.f / ls;
#pragma unroll
          for (int j = 0; j < 4; ++j)
            ep16[lrow * 64 + j * 16 + fr] = f2bf(acc[i][j][r] * inv);
        }
      }
#pragma unroll
      for (int it = 0; it < 4; ++it) {
        const int lr = it * 8 + (lane >> 3);
        const int ch = (lane & 7) << 3;
        int4 d = *(const int4*)(ep16 + lr * 64 + ch);
        *reinterpret_cast<int4*>(Cg + (long)(rb + h * 32 + lr) * N + cb + ch) = d;
      }
      wg_barrier();
    }
  }
}

// ---------------- LayerNorm over rows of 768, bf16 in ----------------
__global__ __launch_bounds__(192) void layernorm_rows(const u16* __restrict__ in,
                                                      const float* __restrict__ gamma,
                                                      const float* __restrict__ beta,
                                                      float* __restrict__ outf,
                                                      u16* __restrict__ outb) {
  const int row = blockIdx.x;
  const int t = threadIdx.x;
  ushort4 uv = ((const ushort4*)(in + (long)row * D_MODEL))[t];
  float v0 = bf2f(uv.x), v1 = bf2f(uv.y), v2 = bf2f(uv.z), v3 = bf2f(uv.w);
  float s1 = v0 + v1 + v2 + v3;
  float s2 = v0 * v0 + v1 * v1 + v2 * v2 + v3 * v3;
#pragma unroll
  for (int o = 32; o; o >>= 1) { s1 += __shfl_xor(s1, o); s2 += __shfl_xor(s2, o); }
  __shared__ float r1[3], r2[3];
  const int wv = t >> 6, ln = t & 63;
  if (ln == 0) { r1[wv] = s1; r2[wv] = s2; }
  __syncthreads();
  s1 = r1[0] + r1[1] + r1[2];
  s2 = r2[0] + r2[1] + r2[2];
  const float mu = s1 * (1.f / 768.f);
  const float var = s2 * (1.f / 768.f) - mu * mu;
  const float rstd = rsqrtf(var + 1e-12f);
  float4 gv = ((const float4*)gamma)[t];
  float4 bv = ((const float4*)beta)[t];
  float o0 = (v0 - mu) * rstd * gv.x + bv.x;
  float o1 = (v1 - mu) * rstd * gv.y + bv.y;
  float o2 = (v2 - mu) * rstd * gv.z + bv.z;
  float o3 = (v3 - mu) * rstd * gv.w + bv.w;
  if (outf) {
    float4 ov = {o0, o1, o2, o3};
    ((float4*)(outf + (long)row * D_MODEL))[t] = ov;
  }
  if (outb) {
    ushort4 ob;
    ob.x = f2bf(o0); ob.y = f2bf(o1); ob.z = f2bf(o2); ob.w = f2bf(o3);
    ((ushort4*)(outb + (long)row * D_MODEL))[t] = ob;
  }
}

// ---------------- workspace layout (bytes), stream-ordered aliasing ----------------
static const size_t OFF_WP   = 0;          // 1179648
static const size_t OFF_W1   = 1179648;    // 2359296
static const size_t OFF_W2   = 3538944;    // 2359296 -> 5898240
static const size_t OFF_LSUM = 5898240;    // 65536 [legacy, still zeroed by cvt]
static const size_t OFF_BQKV = 5963776;    // 9216 (pad to 6291456)
static const size_t OFF_QB   = 6291456;    // fp8 12582912  (QB,KB contiguous)
static const size_t OFF_KB   = 18874368;   // fp8 12582912
static const size_t OFF_VT   = 31457280;   // fp8 12582912 [dead after DIV]
static const size_t OFF_EB   = 44040192;   // fp8 33554432 [dead after DIV]
static const size_t OFF_CTX  = 77594624;   // bf16 25165824 [dead after proj]
static const size_t OFF_XB   = 102760448;  // bf16 25165824 [dead after proj]
static const size_t OFF_WQKV = 127926272;  // bf16 3538944 -> 131465216
static const size_t OFF_M1B  = 131465216;  // bf16 50331648 -> 181796864 total
// aliases: PB=QB+KB (25 MB); HB=EB head (25 MB); M2B=CTX region;
// LS32 (2MB partial sums, live EXP..DIV) = M1B head (M1B written later by MLP1)

extern "C" void kernel_launch(void* const* d_in, const int* in_sizes, int n_in,
                              void* d_out, int out_size, void* d_ws, size_t ws_size,
                              hipStream_t stream) {
  const float* x   = (const float*)d_in[0];
  const float* Wq  = (const float*)d_in[1];
  const float* bq  = (const float*)d_in[2];
  const float* Wk  = (const float*)d_in[3];
  const float* bk  = (const float*)d_in[4];
  const float* Wv  = (const float*)d_in[5];
  const float* bv  = (const float*)d_in[6];
  const float* Wp  = (const float*)d_in[7];
  const float* bp  = (const float*)d_in[8];
  const float* g1  = (const float*)d_in[9];
  const float* be1 = (const float*)d_in[10];
  const float* W1  = (const float*)d_in[11];
  const float* b1  = (const float*)d_in[12];
  const float* W2  = (const float*)d_in[13];
  const float* b2  = (const float*)d_in[14];
  const float* g2  = (const float*)d_in[15];
  const float* be2 = (const float*)d_in[16];

  char* ws = (char*)d_ws;
  u16*   WPB  = (u16*)(ws + OFF_WP);
  u16*   W1B  = (u16*)(ws + OFF_W1);
  u16*   W2B  = (u16*)(ws + OFF_W2);
  float* LSUM = (float*)(ws + OFF_LSUM);
  float* BQKV = (float*)(ws + OFF_BQKV);
  u8*    QB   = (u8*)(ws + OFF_QB);
  u8*    KB   = (u8*)(ws + OFF_KB);
  u8*    VT   = (u8*)(ws + OFF_VT);
  u8*    EB   = (u8*)(ws + OFF_EB);
  u16*   CTX  = (u16*)(ws + OFF_CTX);
  u16*   XB   = (u16*)(ws + OFF_XB);
  u16*   WQKV = (u16*)(ws + OFF_WQKV);
  u16*   M1B  = (u16*)(ws + OFF_M1B);
  // aliases (stream-ordered lifetimes)
  u16*   PB   = (u16*)(ws + OFF_QB);    // after EXP frees QB+KB
  u16*   HB   = (u16*)(ws + OFF_EB);    // after DIV frees EB
  u16*   M2B  = (u16*)(ws + OFF_CTX);   // after proj frees CTX
  float* LS32 = (float*)(ws + OFF_M1B); // partial sums, dead before MLP1 writes M1B

  dim3 blk(256), blkg(512), blkl(192);

  // all f32->bf16 conversions + bias concat + LSUM zero, one kernel
  cvt_all<<<dim3(16915), blk, 0, stream>>>(x, Wq, Wk, Wv, Wp, W1, W2, bq, bk, bv,
                                           XB, WQKV, WPB, W1B, W2B, BQKV, LSUM);

  // fused QKV projection (bf16 core, fp8 outputs): Q,K row-major fp8; V -> VT fp8 transposed
  // 128x256 tile, 8 waves: 1152 blocks at 2/CU (halved A-panel rereads vs 128^2)
  gemm_bt512<<<dim3(128, 9, 1), blkg, 0, stream>>>(XB, WQKV, QB,
      NROWS, 3 * D_MODEL, D_MODEL, 0, 0, 0, BQKV, (const u16*)VT, nullptr, 0.f);

  // scores: E' = exp(Q K^T / sqrt(D) - 3) fp8, 64-col partial sums -> LS32 (plain stores)
  // DEPTH=2: 4 blocks/CU -> 2048 tiles = exactly 2.0 rounds of 1024 slots
  const float sc = 1.0f / sqrtf((float)D_MODEL);
  gemm_f8<EPI_EXP, 2><<<dim3(16, 16, 8), blk, 0, stream>>>(QB, KB, EB,
      SEQLEN, SEQLEN, D_MODEL,
      (long)SEQLEN * D_MODEL, (long)SEQLEN * D_MODEL, (long)SEQLEN * SEQLEN,
      LS32, sc);
  // context: Ctx = (E' V) / rowsum (bf16 out); grid 16x6x8 = 768 = 1.0 round at 3/CU
  gemm_f8<EPI_DIV, 3><<<dim3(16, 6, 8), blk, 0, stream>>>(EB, VT, CTX,
      SEQLEN, D_MODEL, SEQLEN,
      (long)SEQLEN * SEQLEN, (long)D_MODEL * SEQLEN, (long)SEQLEN * D_MODEL,
      LS32, 0.f);
  // proj + residual (bf16): PB = bf16(x + Ctx Wp^T + bp); 768 blocks = 1.0 round
  gemm_bt<EPI_RES><<<dim3(128, 6, 1), blk, 0, stream>>>(CTX, WPB, PB,
      NROWS, D_MODEL, D_MODEL, 0, 0, 0, bp, XB, nullptr, 0.f);
  // LN1 -> HB (bf16)
  layernorm_rows<<<dim3(NROWS), blkl, 0, stream>>>(PB, g1, be1, nullptr, HB);
  // MLP1 + tanh-gelu -> M1B (bf16); 1536 blocks = 2.0 rounds  [overwrites LS32 - dead]
  gemm_bt<EPI_GELU><<<dim3(128, 12, 1), blk, 0, stream>>>(HB, W1B, M1B,
      NROWS, D_HID, D_MODEL, 0, 0, 0, b1, nullptr, nullptr, 0.f);
  // MLP2 + residual (bf16): M2B = bf16(h + M1 W2^T + b2); 768 blocks = 1.0 round
  gemm_bt<EPI_RES><<<dim3(128, 6, 1), blk, 0, stream>>>(M1B, W2B, M2B,
      NROWS, D_MODEL, D_HID, 0, 0, 0, b2, HB, nullptr, 0.f);
  // LN2 -> d_out (fp32)
  layernorm_rows<<<dim3(NROWS), blkl, 0, stream>>>(M2B, g2, be2, (float*)d_out, nullptr);

  (void)in_sizes; (void)n_in; (void)out_size; (void)ws_size;
}

// Round 9
// 450.056 us; speedup vs baseline: 1.1731x; 1.0306x over previous
//
#include <hip/hip_runtime.h>
#include <math.h>

#define D_MODEL 768
#define D_HID   1536
#define N_BATCH 8
#define SEQLEN  2048
#define NROWS   (N_BATCH*SEQLEN)   // 16384

typedef unsigned short u16;
typedef unsigned char  u8;
typedef __attribute__((ext_vector_type(8))) short bfrag;   // 8 x bf16 (4 VGPRs)
typedef __attribute__((ext_vector_type(4))) float facc;    // 4 x fp32 acc

__device__ __forceinline__ u16 f2bf(float f) {
  unsigned u = __float_as_uint(f);
  u += 0x7fffu + ((u >> 16) & 1u);
  return (u16)(u >> 16);
}
__device__ __forceinline__ float bf2f(u16 u) {
  return __uint_as_float((unsigned)u << 16);
}
__device__ __forceinline__ u8 f2fp8(float f) {   // OCP e4m3 on gfx950
  return (u8)(__builtin_amdgcn_cvt_pk_fp8_f32(f, f, 0, 0) & 0xff);
}

__device__ __forceinline__ void async16(const void* g, void* l) {
  __builtin_amdgcn_global_load_lds((const __attribute__((address_space(1))) void*)g,
                                   (__attribute__((address_space(3))) void*)l,
                                   16, 0, 0);
}
// raw barrier: no implicit vmcnt(0) drain (unlike __syncthreads), full compiler fence
__device__ __forceinline__ void wg_barrier() {
  asm volatile("" ::: "memory");
  __builtin_amdgcn_s_barrier();
  asm volatile("" ::: "memory");
}
#define VMCNT(n) asm volatile("s_waitcnt vmcnt(" #n ")" ::: "memory")

// ------- fused f32->bf16 conversion of all operands + bias concat + LSUM zero -------
__global__ __launch_bounds__(256) void cvt_all(
    const float* __restrict__ x,  const float* __restrict__ Wq,
    const float* __restrict__ Wk, const float* __restrict__ Wv,
    const float* __restrict__ Wp, const float* __restrict__ W1,
    const float* __restrict__ W2, const float* __restrict__ bq,
    const float* __restrict__ bk, const float* __restrict__ bv,
    u16* __restrict__ XB, u16* __restrict__ WQKV, u16* __restrict__ WPB,
    u16* __restrict__ W1B, u16* __restrict__ W2B, float* __restrict__ BQKV,
    float* __restrict__ LSUM) {
  long i = (long)blockIdx.x * 256 + threadIdx.x;
  const float* src; u16* dst; long off;
  if      (i < 3145728) { src = x;  dst = XB;             off = i; }
  else if (i < 3293184) { src = Wq; dst = WQKV;           off = i - 3145728; }
  else if (i < 3440640) { src = Wk; dst = WQKV + 589824;  off = i - 3293184; }
  else if (i < 3588096) { src = Wv; dst = WQKV + 1179648; off = i - 3440640; }
  else if (i < 3735552) { src = Wp; dst = WPB;            off = i - 3588096; }
  else if (i < 4030464) { src = W1; dst = W1B;            off = i - 3735552; }
  else if (i < 4325376) { src = W2; dst = W2B;            off = i - 4030464; }
  else if (i < 4325952) {
    long j = i - 4325376;   // 0..575 -> BQKV[j] (f4), concatenated bq|bk|bv
    const float* s = (j < 192) ? bq : (j < 384) ? bk : bv;
    long o = (j < 192) ? j : (j < 384) ? j - 192 : j - 384;
    ((float4*)BQKV)[j] = ((const float4*)s)[o];
    return;
  } else if (i < 4330048) {
    float4 zz = {0.f, 0.f, 0.f, 0.f};
    ((float4*)LSUM)[i - 4325952] = zz;
    return;
  } else return;
  float4 v = ((const float4*)src)[off];
  ushort4 o4;
  o4.x = f2bf(v.x); o4.y = f2bf(v.y); o4.z = f2bf(v.z); o4.w = f2bf(v.w);
  *reinterpret_cast<ushort4*>(dst + off * 4) = o4;
}

enum { EPI_EXP = 1, EPI_DIV = 2, EPI_GELU = 4, EPI_QKV = 5, EPI_RES = 6 };

// ===== GEMM bf16: C = A*B^T, tile 128x256, BK=32, 8 waves (512 thr), triple-buffered =====
// Round-5 proven structure: counted vmcnt, no drain, (r>>1)&3 swizzle. Now templated:
// EPI_QKV (fp8 Q/K + transposed V), EPI_GELU (bf16 + tanh-gelu), EPI_RES (bf16 + bias
// + residual). Epilogues are per-wave-private 64x64 blocks (8 x 8KB = 64KB <= 72KB LDS).
template<int EPI>
__global__ __launch_bounds__(512, 2)
void gemm_bt512(const u16* __restrict__ Aall, const u16* __restrict__ Ball,
                void* __restrict__ Cout,
                int M, int N, int K,
                long sA, long sB, long sC,
                const float* __restrict__ bias,
                const u16* __restrict__ resid,   // QKV: VT out (fp8); RES: residual
                float* __restrict__ lsum, float scale)
{
  __shared__ __align__(16) char smem[73728];
  const u16* A = Aall;
  const u16* B = Ball;
  const int bm = blockIdx.x, bn = blockIdx.y;
  const int tid = (int)threadIdx.x;
  const int lane = tid & 63, wv = tid >> 6;
  const int wr = wv >> 2, wc = wv & 3;               // wave grid 2x4 (64x64 each)

  facc acc[4][4] = {};

  const int srow2 = tid >> 2;                         // 0..127
  const int c4 = tid & 3;
  const int skey = (srow2 >> 1) & 3;
  const int sc = ((c4 ^ skey) << 3);                  // source elem offset in row
  const u16* Abase = A + (long)(bm * 128) * K;
  const u16* Bbase = B + (long)(bn * 256) * K;
  const int fr = lane & 15, g0 = lane >> 4;
  const int rkey = (fr >> 1) & 3;
  const int nt = K >> 5;                              // 24 or 48

  auto STAGE = [&](int t, int b) {
    char* Asb = smem + b * 24576;
    char* Bsb = Asb + 8192;
    const long k0 = (long)t << 5;
    async16(Abase + (long)srow2 * K + k0 + sc, Asb + tid * 16);
#pragma unroll
    for (int p = 0; p < 2; ++p)
      async16(Bbase + (long)(p * 128 + srow2) * K + k0 + sc, Bsb + p * 8192 + tid * 16);
  };

  STAGE(0, 0); STAGE(1, 1);
  int rb_ = 0, sb_ = 2;
  for (int t = 0; t < nt; ++t) {
    if (t < nt - 1) { VMCNT(3); } else { VMCNT(0); }  // tile t landed; t+1 stays in flight
    wg_barrier();                                     // all waves: t in LDS, t-1 reads done
    if (t + 2 < nt) STAGE(t + 2, sb_);
    const u16* As = (const u16*)(smem + rb_ * 24576);
    const u16* Bs = As + 4096;
    bfrag af[4], bf[4];
#pragma unroll
    for (int i = 0; i < 4; ++i) {
      const int r = wr * 64 + i * 16 + fr;
      af[i] = *(const bfrag*)(As + r * 32 + ((g0 ^ rkey) << 3));
    }
#pragma unroll
    for (int j = 0; j < 4; ++j) {
      const int r = wc * 64 + j * 16 + fr;
      bf[j] = *(const bfrag*)(Bs + r * 32 + ((g0 ^ rkey) << 3));
    }
    __builtin_amdgcn_s_setprio(1);
#pragma unroll
    for (int i = 0; i < 4; ++i)
#pragma unroll
      for (int j = 0; j < 4; ++j)
        acc[i][j] = __builtin_amdgcn_mfma_f32_16x16x32_bf16(af[i], bf[j], acc[i][j], 0, 0, 0);
    __builtin_amdgcn_s_setprio(0);
    rb_ = (rb_ == 2) ? 0 : rb_ + 1;
    sb_ = (sb_ == 2) ? 0 : sb_ + 1;
  }
  wg_barrier();   // all reads done before epilogue overlays LDS

  // ---- epilogue ---- 16x16 C/D layout: col = lane&15, row = (lane>>4)*4 + reg
  const int rb = bm * 128 + wr * 64;
  const int cb = bn * 256 + wc * 64;
  const int quad = lane >> 4;

  if constexpr (EPI == EPI_QKV) {
    const int c64 = bn * 4 + wc;         // 0..35
    const int which = c64 / 12;          // 0=Q,1=K,2=V (boundaries at multiples of 4)
    float bj[4];
#pragma unroll
    for (int j = 0; j < 4; ++j) bj[j] = bias[cb + j * 16 + fr];
    if (which == 2) {
      u8* VT_ = (u8*)resid;
      const int zb = rb >> 11;
      const int seqb = (rb & 2047) + quad * 4;
      const int dimb = (c64 - 24) * 64;
#pragma unroll
      for (int i = 0; i < 4; ++i) {
#pragma unroll
        for (int j = 0; j < 4; ++j) {
          const int dim = dimb + j * 16 + fr;
          unsigned v01 = __builtin_amdgcn_cvt_pk_fp8_f32(acc[i][j][0] + bj[j],
                                                         acc[i][j][1] + bj[j], 0, 0);
          unsigned v23 = __builtin_amdgcn_cvt_pk_fp8_f32(acc[i][j][2] + bj[j],
                                                         acc[i][j][3] + bj[j], 0, 0);
          unsigned w = (v01 & 0xffffu) | (v23 << 16);
          *reinterpret_cast<unsigned*>(VT_ + (long)zb * D_MODEL * SEQLEN +
                                       (long)dim * SEQLEN + seqb + i * 16) = w;
        }
      }
      return;
    }
    u8* ep8 = (u8*)(smem + wv * 8192);   // 64x64 fp8 per wave
    u8* Cg = (u8*)Cout + (long)which * NROWS * D_MODEL;
    const int cbo = (c64 - which * 12) * 64;
#pragma unroll
    for (int i = 0; i < 4; ++i)
#pragma unroll
      for (int r = 0; r < 4; ++r) {
        const int lrow = i * 16 + quad * 4 + r;
#pragma unroll
        for (int j = 0; j < 4; ++j)
          ep8[lrow * 64 + j * 16 + fr] = f2fp8(acc[i][j][r] + bj[j]);
      }
#pragma unroll
    for (int it = 0; it < 4; ++it) {
      const int lr = it * 16 + (lane >> 2);
      const int ch = (lane & 3) << 4;
      int4 d = *(const int4*)(ep8 + lr * 64 + ch);
      *reinterpret_cast<int4*>(Cg + (long)(rb + lr) * D_MODEL + cbo + ch) = d;
    }
  } else if constexpr (EPI == EPI_GELU) {
    u16* ep16 = (u16*)(smem + wv * 8192);   // 64x64 bf16 per wave (8KB)
    u16* Cg = (u16*)Cout;
    float bj[4];
#pragma unroll
    for (int j = 0; j < 4; ++j) bj[j] = bias[cb + j * 16 + fr];
#pragma unroll
    for (int i = 0; i < 4; ++i) {
#pragma unroll
      for (int r = 0; r < 4; ++r) {
        const int lrow = i * 16 + quad * 4 + r;
#pragma unroll
        for (int j = 0; j < 4; ++j) {
          float t = acc[i][j][r] + bj[j];
          float y = 0.7978845608f * (t + 0.044715f * t * t * t);
          float e = __expf(-2.f * fabsf(y));
          float th = (1.f - e) / (1.f + e);
          th = (y < 0.f) ? -th : th;
          ep16[lrow * 64 + j * 16 + fr] = f2bf(0.5f * t * (1.f + th));
        }
      }
    }
#pragma unroll
    for (int it = 0; it < 8; ++it) {
      const int lr = it * 8 + (lane >> 3);
      const int ch = (lane & 7) << 3;
      int4 d = *(const int4*)(ep16 + lr * 64 + ch);
      *reinterpret_cast<int4*>(Cg + (long)(rb + lr) * N + cb + ch) = d;
    }
  } else {
    // EPI_RES: bf16 out = acc + bias + bf16 residual (two 32-row f32 half-passes)
    float* ep32 = (float*)(smem + wv * 8192);   // 32x64 f32 per wave per pass (8KB)
    u16* Cg = (u16*)Cout;
#pragma unroll
    for (int h = 0; h < 2; ++h) {
#pragma unroll
      for (int i2 = 0; i2 < 2; ++i2) {
        const int i = h * 2 + i2;
#pragma unroll
        for (int r = 0; r < 4; ++r) {
          const int lrow = i2 * 16 + quad * 4 + r;
#pragma unroll
          for (int j = 0; j < 4; ++j)
            ep32[lrow * 64 + j * 16 + fr] = acc[i][j][r];
        }
      }
#pragma unroll
      for (int it = 0; it < 8; ++it) {
        const int lr = it * 4 + (lane >> 4);
        const int ch = (lane & 15) << 2;
        float4 d = *(const float4*)(ep32 + lr * 64 + ch);
        const int row = rb + h * 32 + lr;
        const int gcol = cb + ch;
        const long gi = (long)row * N + gcol;
        ushort4 rv = *(const ushort4*)(resid + gi);
        float4 bb = *(const float4*)(bias + gcol);
        ushort4 o;
        o.x = f2bf(d.x + bb.x + bf2f(rv.x));
        o.y = f2bf(d.y + bb.y + bf2f(rv.y));
        o.z = f2bf(d.z + bb.z + bf2f(rv.z));
        o.w = f2bf(d.w + bb.w + bf2f(rv.w));
        *reinterpret_cast<ushort4*>(Cg + gi) = o;
      }
    }
  }
  (void)lsum; (void)scale; (void)M; (void)sA; (void)sB; (void)sC;
}

// ===== GEMM fp8 e4m3: C = A*B^T, tile 128x128, BK=64 bytes, 4 waves =====
// DEPTH=3: triple-buffer 48KB, 3 blocks/CU. DEPTH=2: double-buffer 32KB, 4 blocks/CU (EXP).
// lsum is a PARTITIONED partial-sum array (no atomics): EXP plain-stores its 64-col
// partial to slot (z*M+row)*32 + bn*2 + wc; DIV gathers 32 partials via float2-per-lane
// + shfl_xor tree.
template<int EPI, int DEPTH>
__global__ __launch_bounds__(256, 6 - DEPTH)
void gemm_f8(const u8* __restrict__ Aall, const u8* __restrict__ Ball,
             void* __restrict__ Cout,
             int M, int N, int K,           // K in elements == bytes
             long sA, long sB, long sC,
             float* __restrict__ lsum, float scale)
{
  __shared__ __align__(16) char smem[DEPTH * 16384];
  const int z = blockIdx.z;
  const u8* A = Aall + (long)z * sA;
  const u8* B = Ball + (long)z * sB;
  const int bm = blockIdx.x, bn = blockIdx.y;
  const int tid = (int)threadIdx.x;
  const int lane = tid & 63, wv = tid >> 6;
  const int wr = wv >> 1, wc = wv & 1;

  facc acc[4][4] = {};

  const int srow2 = tid >> 2;                          // 0..63
  const int c4 = tid & 3;
  const int skey = (srow2 >> 1) & 3;
  const int scb = ((c4 ^ skey) << 4);
  const u8* Abase = A + (long)(bm * 128) * K;
  const u8* Bbase = B + (long)(bn * 128) * K;
  const int fr = lane & 15, g0 = lane >> 4;
  const int rkey = (fr >> 1) & 3;
  const int nt = K >> 6;

  auto STAGE = [&](int t, int b) {
    char* Asb = smem + b * 16384;
    char* Bsb = Asb + 8192;
    const long k0 = (long)t << 6;
#pragma unroll
    for (int p = 0; p < 2; ++p) {
      async16(Abase + (long)(p * 64 + srow2) * K + k0 + scb, Asb + p * 4096 + tid * 16);
      async16(Bbase + (long)(p * 64 + srow2) * K + k0 + scb, Bsb + p * 4096 + tid * 16);
    }
  };

  auto COMPUTE = [&](int buf) {
    const u8* As = (const u8*)(smem + buf * 16384);
    const u8* Bs = As + 8192;
#pragma unroll
    for (int s = 0; s < 2; ++s) {     // 2 K-substeps of 32 fp8
      long af[4], bf[4];
      const int cc = (s * 2 + (g0 >> 1)) ^ rkey;
      const int h8 = (g0 & 1) << 3;
#pragma unroll
      for (int i = 0; i < 4; ++i) {
        const int r = wr * 64 + i * 16 + fr;
        af[i] = *(const long*)(As + r * 64 + (cc << 4) + h8);
      }
#pragma unroll
      for (int j = 0; j < 4; ++j) {
        const int r = wc * 64 + j * 16 + fr;
        bf[j] = *(const long*)(Bs + r * 64 + (cc << 4) + h8);
      }
      __builtin_amdgcn_s_setprio(1);
#pragma unroll
      for (int i = 0; i < 4; ++i)
#pragma unroll
        for (int j = 0; j < 4; ++j)
          acc[i][j] = __builtin_amdgcn_mfma_f32_16x16x32_fp8_fp8(af[i], bf[j], acc[i][j], 0, 0, 0);
      __builtin_amdgcn_s_setprio(0);
    }
  };

  if constexpr (DEPTH == 3) {
    STAGE(0, 0); STAGE(1, 1);
    int rb_ = 0, sb_ = 2;
    for (int t = 0; t < nt; ++t) {
      if (t < nt - 1) { VMCNT(4); } else { VMCNT(0); }
      wg_barrier();
      if (t + 2 < nt) STAGE(t + 2, sb_);
      COMPUTE(rb_);
      rb_ = (rb_ == 2) ? 0 : rb_ + 1;
      sb_ = (sb_ == 2) ? 0 : sb_ + 1;
    }
    wg_barrier();
  } else {
    STAGE(0, 0); STAGE(1, 1);
    for (int t = 0; t < nt; ++t) {
      if (t < nt - 1) { VMCNT(4); } else { VMCNT(0); }
      wg_barrier();                 // tile t in LDS for all waves
      COMPUTE(t & 1);
      wg_barrier();                 // all waves done reading buf t&1
      if (t + 2 < nt) STAGE(t + 2, t & 1);
    }
  }

  const int rb = bm * 128 + wr * 64;
  const int cb = bn * 128 + wc * 64;
  const int quad = lane >> 4;

  if constexpr (EPI == EPI_EXP) {
    // E' = exp(alpha - 3) in fp8 (range ~[e^-5, e^-1]); 64-col partial row-sums ->
    // private slot (z*M+row)*32 + bn*2 + wc, plain store (no atomics).
    u8* ep8 = (u8*)(smem + wv * 4096);
    u8* Cg = (u8*)Cout + (long)z * sC;
#pragma unroll
    for (int i = 0; i < 4; ++i) {
#pragma unroll
      for (int r = 0; r < 4; ++r) {
        const int lrow = i * 16 + quad * 4 + r;
        const int row = rb + lrow;
        float rs = 0.f;
#pragma unroll
        for (int j = 0; j < 4; ++j) {
          float e = __expf(acc[i][j][r] * scale - 3.0f);
          rs += e;
          ep8[lrow * 64 + j * 16 + fr] = f2fp8(e);
        }
        rs += __shfl_xor(rs, 1);
        rs += __shfl_xor(rs, 2);
        rs += __shfl_xor(rs, 4);
        rs += __shfl_xor(rs, 8);
        if (fr == 0)
          lsum[(((long)z * M + row) << 5) + (bn << 1) + wc] = rs;
      }
    }
#pragma unroll
    for (int it = 0; it < 4; ++it) {
      const int lr = it * 16 + (lane >> 2);
      const int ch = (lane & 3) << 4;
      int4 d = *(const int4*)(ep8 + lr * 64 + ch);
      *reinterpret_cast<int4*>(Cg + (long)(rb + lr) * N + cb + ch) = d;
    }
  } else {
    // EPI_DIV: bf16 out = acc / rowsum; rowsum = Sum of 32 partials, gathered as
    // float2-per-lane (fr*2) + shfl_xor tree within each 16-lane group.
    u16* ep16 = (u16*)(smem + wv * 4096);
    u16* Cg = (u16*)Cout + (long)z * sC;
#pragma unroll
    for (int h = 0; h < 2; ++h) {
#pragma unroll
      for (int i2 = 0; i2 < 2; ++i2) {
        const int i = h * 2 + i2;
#pragma unroll
        for (int r = 0; r < 4; ++r) {
          const int lrow = i2 * 16 + quad * 4 + r;
          const int row = rb + h * 32 + lrow;
          const float2 p2 = *reinterpret_cast<const float2*>(
              lsum + (((long)z * M + row) << 5) + (fr << 1));
          float ls = p2.x + p2.y;
          ls += __shfl_xor(ls, 1);
          ls += __shfl_xor(ls, 2);
          ls += __shfl_xor(ls, 4);
          ls += __shfl_xor(ls, 8);
          const float inv = 1.f / ls;
#pragma unroll
          for (int j = 0; j < 4; ++j)
            ep16[lrow * 64 + j * 16 + fr] = f2bf(acc[i][j][r] * inv);
        }
      }
#pragma unroll
      for (int it = 0; it < 4; ++it) {
        const int lr = it * 8 + (lane >> 3);
        const int ch = (lane & 7) << 3;
        int4 d = *(const int4*)(ep16 + lr * 64 + ch);
        *reinterpret_cast<int4*>(Cg + (long)(rb + h * 32 + lr) * N + cb + ch) = d;
      }
      wg_barrier();
    }
  }
}

// ---------------- LayerNorm over rows of 768, bf16 in ----------------
__global__ __launch_bounds__(192) void layernorm_rows(const u16* __restrict__ in,
                                                      const float* __restrict__ gamma,
                                                      const float* __restrict__ beta,
                                                      float* __restrict__ outf,
                                                      u16* __restrict__ outb) {
  const int row = blockIdx.x;
  const int t = threadIdx.x;
  ushort4 uv = ((const ushort4*)(in + (long)row * D_MODEL))[t];
  float v0 = bf2f(uv.x), v1 = bf2f(uv.y), v2 = bf2f(uv.z), v3 = bf2f(uv.w);
  float s1 = v0 + v1 + v2 + v3;
  float s2 = v0 * v0 + v1 * v1 + v2 * v2 + v3 * v3;
#pragma unroll
  for (int o = 32; o; o >>= 1) { s1 += __shfl_xor(s1, o); s2 += __shfl_xor(s2, o); }
  __shared__ float r1[3], r2[3];
  const int wv = t >> 6, ln = t & 63;
  if (ln == 0) { r1[wv] = s1; r2[wv] = s2; }
  __syncthreads();
  s1 = r1[0] + r1[1] + r1[2];
  s2 = r2[0] + r2[1] + r2[2];
  const float mu = s1 * (1.f / 768.f);
  const float var = s2 * (1.f / 768.f) - mu * mu;
  const float rstd = rsqrtf(var + 1e-12f);
  float4 gv = ((const float4*)gamma)[t];
  float4 bv = ((const float4*)beta)[t];
  float o0 = (v0 - mu) * rstd * gv.x + bv.x;
  float o1 = (v1 - mu) * rstd * gv.y + bv.y;
  float o2 = (v2 - mu) * rstd * gv.z + bv.z;
  float o3 = (v3 - mu) * rstd * gv.w + bv.w;
  if (outf) {
    float4 ov = {o0, o1, o2, o3};
    ((float4*)(outf + (long)row * D_MODEL))[t] = ov;
  }
  if (outb) {
    ushort4 ob;
    ob.x = f2bf(o0); ob.y = f2bf(o1); ob.z = f2bf(o2); ob.w = f2bf(o3);
    ((ushort4*)(outb + (long)row * D_MODEL))[t] = ob;
  }
}

// ---------------- workspace layout (bytes), stream-ordered aliasing ----------------
static const size_t OFF_WP   = 0;          // 1179648
static const size_t OFF_W1   = 1179648;    // 2359296
static const size_t OFF_W2   = 3538944;    // 2359296 -> 5898240
static const size_t OFF_LSUM = 5898240;    // 65536 [legacy, still zeroed by cvt]
static const size_t OFF_BQKV = 5963776;    // 9216 (pad to 6291456)
static const size_t OFF_QB   = 6291456;    // fp8 12582912  (QB,KB contiguous)
static const size_t OFF_KB   = 18874368;   // fp8 12582912
static const size_t OFF_VT   = 31457280;   // fp8 12582912 [dead after DIV]
static const size_t OFF_EB   = 44040192;   // fp8 33554432 [dead after DIV]
static const size_t OFF_CTX  = 77594624;   // bf16 25165824 [dead after proj]
static const size_t OFF_XB   = 102760448;  // bf16 25165824 [dead after proj]
static const size_t OFF_WQKV = 127926272;  // bf16 3538944 -> 131465216
static const size_t OFF_M1B  = 131465216;  // bf16 50331648 -> 181796864 total
// aliases: PB=QB+KB (25 MB); HB=EB head (25 MB); M2B=CTX region;
// LS32 (2MB partial sums, live EXP..DIV) = M1B head (M1B written later by MLP1)

extern "C" void kernel_launch(void* const* d_in, const int* in_sizes, int n_in,
                              void* d_out, int out_size, void* d_ws, size_t ws_size,
                              hipStream_t stream) {
  const float* x   = (const float*)d_in[0];
  const float* Wq  = (const float*)d_in[1];
  const float* bq  = (const float*)d_in[2];
  const float* Wk  = (const float*)d_in[3];
  const float* bk  = (const float*)d_in[4];
  const float* Wv  = (const float*)d_in[5];
  const float* bv  = (const float*)d_in[6];
  const float* Wp  = (const float*)d_in[7];
  const float* bp  = (const float*)d_in[8];
  const float* g1  = (const float*)d_in[9];
  const float* be1 = (const float*)d_in[10];
  const float* W1  = (const float*)d_in[11];
  const float* b1  = (const float*)d_in[12];
  const float* W2  = (const float*)d_in[13];
  const float* b2  = (const float*)d_in[14];
  const float* g2  = (const float*)d_in[15];
  const float* be2 = (const float*)d_in[16];

  char* ws = (char*)d_ws;
  u16*   WPB  = (u16*)(ws + OFF_WP);
  u16*   W1B  = (u16*)(ws + OFF_W1);
  u16*   W2B  = (u16*)(ws + OFF_W2);
  float* LSUM = (float*)(ws + OFF_LSUM);
  float* BQKV = (float*)(ws + OFF_BQKV);
  u8*    QB   = (u8*)(ws + OFF_QB);
  u8*    KB   = (u8*)(ws + OFF_KB);
  u8*    VT   = (u8*)(ws + OFF_VT);
  u8*    EB   = (u8*)(ws + OFF_EB);
  u16*   CTX  = (u16*)(ws + OFF_CTX);
  u16*   XB   = (u16*)(ws + OFF_XB);
  u16*   WQKV = (u16*)(ws + OFF_WQKV);
  u16*   M1B  = (u16*)(ws + OFF_M1B);
  // aliases (stream-ordered lifetimes)
  u16*   PB   = (u16*)(ws + OFF_QB);    // after EXP frees QB+KB
  u16*   HB   = (u16*)(ws + OFF_EB);    // after DIV frees EB
  u16*   M2B  = (u16*)(ws + OFF_CTX);   // after proj frees CTX
  float* LS32 = (float*)(ws + OFF_M1B); // partial sums, dead before MLP1 writes M1B

  dim3 blk(256), blkg(512), blkl(192);

  // all f32->bf16 conversions + bias concat + LSUM zero, one kernel
  cvt_all<<<dim3(16915), blk, 0, stream>>>(x, Wq, Wk, Wv, Wp, W1, W2, bq, bk, bv,
                                           XB, WQKV, WPB, W1B, W2B, BQKV, LSUM);

  // fused QKV projection (bf16 core, fp8 outputs): Q,K row-major fp8; V -> VT fp8 transposed
  gemm_bt512<EPI_QKV><<<dim3(128, 9, 1), blkg, 0, stream>>>(XB, WQKV, QB,
      NROWS, 3 * D_MODEL, D_MODEL, 0, 0, 0, BQKV, (const u16*)VT, nullptr, 0.f);

  // scores: E' = exp(Q K^T / sqrt(D) - 3) fp8, 64-col partial sums -> LS32 (plain stores)
  // DEPTH=2: 4 blocks/CU -> 2048 tiles = exactly 2.0 rounds of 1024 slots
  const float sc = 1.0f / sqrtf((float)D_MODEL);
  gemm_f8<EPI_EXP, 2><<<dim3(16, 16, 8), blk, 0, stream>>>(QB, KB, EB,
      SEQLEN, SEQLEN, D_MODEL,
      (long)SEQLEN * D_MODEL, (long)SEQLEN * D_MODEL, (long)SEQLEN * SEQLEN,
      LS32, sc);
  // context: Ctx = (E' V) / rowsum (bf16 out); grid 16x6x8 = 768 = 1.0 round at 3/CU
  gemm_f8<EPI_DIV, 3><<<dim3(16, 6, 8), blk, 0, stream>>>(EB, VT, CTX,
      SEQLEN, D_MODEL, SEQLEN,
      (long)SEQLEN * SEQLEN, (long)D_MODEL * SEQLEN, (long)SEQLEN * D_MODEL,
      LS32, 0.f);
  // proj + residual (bf16): PB = bf16(x + Ctx Wp^T + bp); 128x256 tile: 384 blocks
  gemm_bt512<EPI_RES><<<dim3(128, 3, 1), blkg, 0, stream>>>(CTX, WPB, PB,
      NROWS, D_MODEL, D_MODEL, 0, 0, 0, bp, XB, nullptr, 0.f);
  // LN1 -> HB (bf16)
  layernorm_rows<<<dim3(NROWS), blkl, 0, stream>>>(PB, g1, be1, nullptr, HB);
  // MLP1 + tanh-gelu -> M1B (bf16); 128x256 tile: 768 blocks  [overwrites LS32 - dead]
  gemm_bt512<EPI_GELU><<<dim3(128, 6, 1), blkg, 0, stream>>>(HB, W1B, M1B,
      NROWS, D_HID, D_MODEL, 0, 0, 0, b1, nullptr, nullptr, 0.f);
  // MLP2 + residual (bf16): M2B = bf16(h + M1 W2^T + b2); 128x256 tile: 384 blocks
  gemm_bt512<EPI_RES><<<dim3(128, 3, 1), blkg, 0, stream>>>(M1B, W2B, M2B,
      NROWS, D_MODEL, D_HID, 0, 0, 0, b2, HB, nullptr, 0.f);
  // LN2 -> d_out (fp32)
  layernorm_rows<<<dim3(NROWS), blkl, 0, stream>>>(M2B, g2, be2, (float*)d_out, nullptr);

  (void)in_sizes; (void)n_in; (void)out_size; (void)ws_size;
}